// Round 7
// baseline (220.203 us; speedup 1.0000x reference)
//
#include <hip/hip_runtime.h>
#include <hip/hip_bf16.h>

// Problem: B=2, S=2048, C=U=1024, H=16, dh=64. I/O FP32.
// cast X->bf16, transpose+cast W->bf16, QKV GEMM (m97-style global_load_lds
// staging, bf16 MFMA, f16 out), transpose V, flash attention (paired qtiles,
// XCD-swizzled blocks, double-buffered LDS K/V with register prefetch,
// S^T/O^T register chaining, fused residual + LN-stats), LN apply.

typedef __bf16 bf16_t;
typedef __bf16 bf16x8 __attribute__((ext_vector_type(8)));
typedef __bf16 bf16x4 __attribute__((ext_vector_type(4)));
typedef _Float16 f16_t;
typedef _Float16 f16x4 __attribute__((ext_vector_type(4)));
typedef _Float16 f16x8 __attribute__((ext_vector_type(8)));
typedef float f32x4 __attribute__((ext_vector_type(4)));

constexpr int Bsz = 2;
constexpr int Seq = 2048;
constexpr int Cdim = 1024;   // == U
constexpr int Udim = 1024;
constexpr int Hn = 16;
constexpr int Dh = 64;
constexpr int Mrows = Bsz * Seq;          // 4096
constexpr int PerBatch = Seq * Udim;      // 2^21

// async global->LDS, 16B per lane; LDS dest = wave-uniform base + lane*16
__device__ __forceinline__ void gload16(const void* g, void* l)
{
    __builtin_amdgcn_global_load_lds(
        (const __attribute__((address_space(1))) void*)g,
        (__attribute__((address_space(3))) void*)l, 16, 0, 0);
}

// ---------------------------------------------------------------- cast X
__global__ __launch_bounds__(256)
void cast_x(const float* __restrict__ X, bf16_t* __restrict__ Xb)
{
    int i = blockIdx.x * 256 + threadIdx.x;     // over float4 groups, 1M total
    float4 v = ((const float4*)X)[i];
    bf16x4 o = { (bf16_t)v.x, (bf16_t)v.y, (bf16_t)v.z, (bf16_t)v.w };
    *(bf16x4*)(Xb + (size_t)i * 4) = o;
}

// ---------------------------------------------------------------- transpose W
__global__ void transpose_w(const float* __restrict__ Wq, const float* __restrict__ Wk,
                            const float* __restrict__ Wv,
                            bf16_t* __restrict__ Tq, bf16_t* __restrict__ Tk,
                            bf16_t* __restrict__ Tv)
{
    int z = blockIdx.z;
    const float* W = (z == 0) ? Wq : (z == 1) ? Wk : Wv;
    bf16_t* T = (z == 0) ? Tq : (z == 1) ? Tk : Tv;
    __shared__ bf16_t t[64][65];
    int x0 = blockIdx.x * 64, y0 = blockIdx.y * 64;
    int tx = threadIdx.x;
    for (int i = threadIdx.y; i < 64; i += 8)
        t[i][tx] = (bf16_t)W[(size_t)(y0 + i) * Cdim + x0 + tx];
    __syncthreads();
    for (int i = threadIdx.y; i < 64; i += 8)
        T[(size_t)(x0 + i) * Cdim + y0 + tx] = t[tx][i];
}

// ---------------------------------------------------------------- QKV GEMM
// m97 structure: 128x128 tile, BK=32, unpadded LDS, global_load_lds width 16.
__global__ __launch_bounds__(256)
void gemm_qkv(const bf16_t* __restrict__ X,
              const bf16_t* __restrict__ Wt0, const bf16_t* __restrict__ Wt1,
              const bf16_t* __restrict__ Wt2,
              const float* __restrict__ b0, const float* __restrict__ b1,
              const float* __restrict__ b2,
              f16_t* __restrict__ O0, f16_t* __restrict__ O1, f16_t* __restrict__ O2)
{
    int z = blockIdx.z;
    const bf16_t* Wt = (z == 0) ? Wt0 : (z == 1) ? Wt1 : Wt2;
    const float* bias = (z == 0) ? b0 : (z == 1) ? b1 : b2;
    f16_t* Og = (z == 0) ? O0 : (z == 1) ? O1 : O2;

    constexpr int Kd = 1024, Nd = 1024;
    __shared__ __align__(16) bf16_t As[128 * 32];   // unpadded: global_load_lds layout
    __shared__ __align__(16) bf16_t Bs[128 * 32];

    int tid = threadIdx.x;
    int wave = tid >> 6, lane = tid & 63, quad = lane >> 4, l16 = lane & 15;
    int wm = (wave & 1) * 64, wn = (wave >> 1) * 64;
    int m0 = blockIdx.y * 128, n0 = blockIdx.x * 128;

    f32x4 acc[4][4] = {};

    int e0 = wave * 512 + lane * 8;
    int r0 = e0 >> 5, c0 = e0 & 31;
    int e1 = e0 + 2048;
    int r1 = e1 >> 5, c1 = e1 & 31;
    const bf16_t* Ag = X + (size_t)m0 * Kd;
    const bf16_t* Bg = Wt + (size_t)n0 * Kd;
    bf16_t* AsW0 = As + wave * 512;          // wave-uniform LDS bases
    bf16_t* AsW1 = As + 2048 + wave * 512;
    bf16_t* BsW0 = Bs + wave * 512;
    bf16_t* BsW1 = Bs + 2048 + wave * 512;

    for (int k0 = 0; k0 < Kd; k0 += 32) {
        gload16(Ag + (size_t)r0 * Kd + k0 + c0, AsW0);
        gload16(Ag + (size_t)r1 * Kd + k0 + c1, AsW1);
        gload16(Bg + (size_t)r0 * Kd + k0 + c0, BsW0);
        gload16(Bg + (size_t)r1 * Kd + k0 + c1, BsW1);
        __syncthreads();

        bf16x8 af[4], bfr[4];
#pragma unroll
        for (int i = 0; i < 4; i++)
            af[i] = *(const bf16x8*)&As[(wm + i * 16 + l16) * 32 + quad * 8];
#pragma unroll
        for (int i = 0; i < 4; i++)
            bfr[i] = *(const bf16x8*)&Bs[(wn + i * 16 + l16) * 32 + quad * 8];
#pragma unroll
        for (int mt = 0; mt < 4; mt++)
#pragma unroll
            for (int nt = 0; nt < 4; nt++)
                acc[mt][nt] = __builtin_amdgcn_mfma_f32_16x16x32_bf16(
                    af[mt], bfr[nt], acc[mt][nt], 0, 0, 0);
        __syncthreads();
    }

#pragma unroll
    for (int nt = 0; nt < 4; nt++) {
        int col = n0 + wn + nt * 16 + l16;
        float bv = bias[col];
#pragma unroll
        for (int mt = 0; mt < 4; mt++) {
            int row = m0 + wm + mt * 16 + quad * 4;
#pragma unroll
            for (int r = 0; r < 4; r++)
                Og[(size_t)(row + r) * Nd + col] = (f16_t)(acc[mt][nt][r] + bv);
        }
    }
}

// ---------------------------------------------------------------- transpose V
// V[4096][1024] f16 -> Vt[b][h][d=64][s=2048] f16
__global__ void transpose_v(const f16_t* __restrict__ V, f16_t* __restrict__ Vt)
{
    int s0 = blockIdx.x * 64;
    int y = blockIdx.y;                 // bh: b = y>>4, h = y&15
    int b = y >> 4, h = y & 15;
    __shared__ f16_t t[64][65];
    int tx = threadIdx.x;
    for (int i = threadIdx.y; i < 64; i += 8)
        t[i][tx] = V[(size_t)(b * Seq + s0 + i) * Udim + h * Dh + tx];
    __syncthreads();
    for (int i = threadIdx.y; i < 64; i += 8)
        Vt[((size_t)y * Dh + i) * Seq + s0 + tx] = t[tx][i];
}

// ---------------------------------------------------------------- attention
// Paired qtiles (p, 31-p) = 33 kv-iters per block; XCD-swizzled block id so
// all 16 p-blocks of one (b,h) share an XCD (K/V L2-resident). Double-
// buffered LDS K/V with register prefetch -> 1 barrier/iter, load latency
// hidden under compute. S^T/O^T register chaining; wave-uniform skip of
// fully-masked diagonal tiles; exp2-domain softmax. Epilogue fuses residual
// and per-batch sum/sumsq stats.
__global__ __launch_bounds__(256)
void attn5(const f16_t* __restrict__ Q, const f16_t* __restrict__ K,
           const f16_t* __restrict__ Vt, const float* __restrict__ X,
           float* __restrict__ R, float* __restrict__ stats)
{
    // id = (bh&7) + 8*(p + 16*(bh>>3)) : 16 p-blocks of one bh -> same id%8
    int id = blockIdx.x;
    int c = id & 7, g = id >> 3;
    int p = g & 15, mhi = g >> 4;
    int bh = (mhi << 3) | c;
    int b = bh >> 4, h = bh & 15;

    int tid = threadIdx.x;
    int w = tid >> 6, lane = tid & 63, quad = lane >> 4, l16 = lane & 15;
    size_t bS = (size_t)b * Seq;

    __shared__ f16_t Ks[2][64][72];   // [buf][kv][d]
    __shared__ f16_t Vs[2][64][72];   // [buf][d][kv]

    const f16_t* Kg = K + bS * Udim + h * Dh;
    const f16_t* Vg = Vt + ((size_t)(b * Hn + h)) * Dh * Seq;

    float s_acc = 0.0f, ss_acc = 0.0f;
    int sr = tid >> 2, sc = (tid & 3) * 16;
    constexpr float SCL = 0.125f * 1.44269504088896340736f;   // /8 then log2e

#pragma unroll
    for (int pass = 0; pass < 2; pass++) {
        int qtile = pass ? (31 - p) : p;
        int nkv = qtile * 64;          // last kv0
        int q0 = qtile * 64 + w * 16;
        int qidx = q0 + l16;

        const f16_t* Qp = Q + (bS + qidx) * Udim + h * Dh;
        f16x8 qf[2];
#pragma unroll
        for (int s = 0; s < 2; s++) qf[s] = *(const f16x8*)(Qp + s * 32 + quad * 8);

        f32x4 Oacc[4] = {};
        float m = -1e30f, l = 0.0f;

        // preload tile 0 into buf 0
        {
            const f16_t* kp = Kg + (size_t)sr * Udim + sc;
            const f16_t* vp = Vg + (size_t)sr * Seq + sc;
            f16x8 k0 = *(const f16x8*)kp;
            f16x8 k1 = *(const f16x8*)(kp + 8);
            f16x8 v0 = *(const f16x8*)vp;
            f16x8 v1 = *(const f16x8*)(vp + 8);
            *(f16x8*)&Ks[0][sr][sc] = k0;
            *(f16x8*)&Ks[0][sr][sc + 8] = k1;
            *(f16x8*)&Vs[0][sr][sc] = v0;
            *(f16x8*)&Vs[0][sr][sc + 8] = v1;
        }
        __syncthreads();

        int buf = 0;
        for (int kv0 = 0; kv0 <= nkv; kv0 += 64) {
            bool have = (kv0 + 64 <= nkv);
            // prefetch next tile into registers (latency overlaps compute)
            f16x8 nk0, nk1, nv0, nv1;
            if (have) {
                const f16_t* kp = Kg + (size_t)(kv0 + 64 + sr) * Udim + sc;
                const f16_t* vp = Vg + (size_t)sr * Seq + kv0 + 64 + sc;
                nk0 = *(const f16x8*)kp;
                nk1 = *(const f16x8*)(kp + 8);
                nv0 = *(const f16x8*)vp;
                nv1 = *(const f16x8*)(vp + 8);
            }

            bool diag = (kv0 == nkv);

            // S^T tiles: A=K[m=kv][k=d] from LDS, B=Q^T from regs
            f32x4 st[4];
#pragma unroll
            for (int t = 0; t < 4; t++) {
                if (!diag || t <= w) {          // wave-uniform branch, static t
                    f32x4 a = {};
#pragma unroll
                    for (int s = 0; s < 2; s++) {
                        f16x8 kf = *(const f16x8*)&Ks[buf][t * 16 + l16][s * 32 + quad * 8];
                        a = __builtin_amdgcn_mfma_f32_16x16x32_f16(kf, qf[s], a, 0, 0, 0);
                    }
                    st[t] = a;
                } else {
                    st[t] = f32x4{-1e30f, -1e30f, -1e30f, -1e30f};
                }
            }

            // softmax in exp2 domain; row = q = l16 (per-lane scalar state)
            float mx = -1e30f;
#pragma unroll
            for (int t = 0; t < 4; t++)
#pragma unroll
                for (int r = 0; r < 4; r++) {
                    float sv = st[t][r] * SCL;
                    if (diag && (kv0 + t * 16 + quad * 4 + r > qidx))
                        sv = -1e30f;     // causal
                    st[t][r] = sv;
                    mx = fmaxf(mx, sv);
                }
            mx = fmaxf(mx, __shfl_xor(mx, 16));
            mx = fmaxf(mx, __shfl_xor(mx, 32));
            float mnew = fmaxf(m, mx);
            float alpha = exp2f(m - mnew);
            float sum = 0.0f;
            f16x4 pf[4];
#pragma unroll
            for (int t = 0; t < 4; t++)
#pragma unroll
                for (int r = 0; r < 4; r++) {
                    float pv = exp2f(st[t][r] - mnew);
                    sum += pv;
                    pf[t][r] = (f16_t)pv;
                }
            sum += __shfl_xor(sum, 16);
            sum += __shfl_xor(sum, 32);
            l = l * alpha + sum;
            m = mnew;
#pragma unroll
            for (int dt = 0; dt < 4; dt++)
#pragma unroll
                for (int r = 0; r < 4; r++) Oacc[dt][r] *= alpha;

            // O^T += V^T . P^T : A = Vs[m=d][k=kv] from LDS
#pragma unroll
            for (int t = 0; t < 4; t++) {
                if (!diag || t <= w) {
#pragma unroll
                    for (int dt = 0; dt < 4; dt++) {
                        f16x4 vf = *(const f16x4*)&Vs[buf][dt * 16 + l16][t * 16 + quad * 4];
                        Oacc[dt] = __builtin_amdgcn_mfma_f32_16x16x16f16(vf, pf[t], Oacc[dt], 0, 0, 0);
                    }
                }
            }

            // write prefetched tile into the other buffer
            if (have) {
                *(f16x8*)&Ks[buf ^ 1][sr][sc] = nk0;
                *(f16x8*)&Ks[buf ^ 1][sr][sc + 8] = nk1;
                *(f16x8*)&Vs[buf ^ 1][sr][sc] = nv0;
                *(f16x8*)&Vs[buf ^ 1][sr][sc + 8] = nv1;
            }
            __syncthreads();
            buf ^= 1;
        }

        // epilogue: resid = O/l + X ; accumulate stats
        float invl = 1.0f / l;
        const float* Xp = X + (bS + qidx) * Udim + h * Dh;
        float* Rp = R + (bS + qidx) * Udim + h * Dh;
#pragma unroll
        for (int dt = 0; dt < 4; dt++) {
            f32x4 xv = *(const f32x4*)(Xp + dt * 16 + quad * 4);
            f32x4 o = Oacc[dt] * invl + xv;
            *(f32x4*)(Rp + dt * 16 + quad * 4) = o;
#pragma unroll
            for (int r = 0; r < 4; r++) {
                s_acc += o[r];
                ss_acc += o[r] * o[r];
            }
        }
    }

    // block-level stats reduction -> 2 atomics
#pragma unroll
    for (int o = 1; o < 64; o <<= 1) {
        s_acc += __shfl_xor(s_acc, o);
        ss_acc += __shfl_xor(ss_acc, o);
    }
    __shared__ float red[8];
    if (lane == 0) { red[w] = s_acc; red[4 + w] = ss_acc; }
    __syncthreads();
    if (tid == 0) {
        atomicAdd(&stats[b], red[0] + red[1] + red[2] + red[3]);
        atomicAdd(&stats[2 + b], red[4] + red[5] + red[6] + red[7]);
    }
}

// ---------------------------------------------------------------- LN apply
__global__ __launch_bounds__(256)
void ln_norm(const float* __restrict__ R, const float* __restrict__ gamma,
             const float* __restrict__ beta, const float* __restrict__ stats,
             float* __restrict__ out)
{
    constexpr int TOT4 = Bsz * Seq * Udim / 4;   // 1M float4
    constexpr float invN = 1.0f / (float)PerBatch;
    float mu[2], inv[2];
    for (int b = 0; b < 2; b++) {
        float m = stats[b] * invN;
        float var = stats[2 + b] * invN - m * m;
        mu[b] = m;
        inv[b] = rsqrtf(var + 1e-5f);
    }
    for (int i = blockIdx.x * blockDim.x + threadIdx.x; i < TOT4;
         i += gridDim.x * blockDim.x) {
        int f = i * 4;
        int b = f >> 21;
        int su = f & (PerBatch - 1);
        float4 rv = *(const float4*)(R + f);
        float4 g = *(const float4*)(gamma + su);
        float4 be = *(const float4*)(beta + su);
        float4 o;
        o.x = (rv.x - mu[b]) * inv[b] * g.x + be.x;
        o.y = (rv.y - mu[b]) * inv[b] * g.y + be.y;
        o.z = (rv.z - mu[b]) * inv[b] * g.z + be.z;
        o.w = (rv.w - mu[b]) * inv[b] * g.w + be.w;
        *(float4*)(out + f) = o;
    }
}

// ---------------------------------------------------------------- launch
extern "C" void kernel_launch(void* const* d_in, const int* in_sizes, int n_in,
                              void* d_out, int out_size, void* d_ws, size_t ws_size,
                              hipStream_t stream)
{
    const float* X     = (const float*)d_in[0];
    const float* Wq    = (const float*)d_in[1];
    const float* bq    = (const float*)d_in[2];
    const float* Wk    = (const float*)d_in[3];
    const float* bk    = (const float*)d_in[4];
    const float* Wv    = (const float*)d_in[5];
    const float* bv    = (const float*)d_in[6];
    const float* gamma = (const float*)d_in[7];
    const float* beta  = (const float*)d_in[8];
    float* out = (float*)d_out;

    char* ws = (char*)d_ws;
    size_t off = 0;
    auto alloc = [&](size_t bytes) -> void* {
        void* p = ws + off;
        off += (bytes + 255) & ~(size_t)255;
        return p;
    };
    bf16_t* Xb = (bf16_t*)alloc((size_t)Mrows * Cdim * 2);
    bf16_t* Tq = (bf16_t*)alloc((size_t)Cdim * Udim * 2);
    bf16_t* Tk = (bf16_t*)alloc((size_t)Cdim * Udim * 2);
    bf16_t* Tv = (bf16_t*)alloc((size_t)Cdim * Udim * 2);
    f16_t*  Qb = (f16_t*)alloc((size_t)Mrows * Udim * 2);
    f16_t*  Kb = (f16_t*)alloc((size_t)Mrows * Udim * 2);
    f16_t*  Vb = (f16_t*)alloc((size_t)Mrows * Udim * 2);
    f16_t*  Vtb = (f16_t*)alloc((size_t)Mrows * Udim * 2);
    float*  Rb = (float*)alloc((size_t)Mrows * Udim * 4);
    float*  stats = (float*)alloc(4 * sizeof(float));

    hipMemsetAsync(stats, 0, 4 * sizeof(float), stream);
    cast_x<<<dim3(Mrows * Cdim / 4 / 256), 256, 0, stream>>>(X, Xb);
    transpose_w<<<dim3(16, 16, 3), dim3(64, 8), 0, stream>>>(Wq, Wk, Wv, Tq, Tk, Tv);
    gemm_qkv<<<dim3(8, 32, 3), 256, 0, stream>>>(Xb, Tq, Tk, Tv, bq, bk, bv, Qb, Kb, Vb);
    transpose_v<<<dim3(Seq / 64, Bsz * Hn), dim3(64, 8), 0, stream>>>(Vb, Vtb);
    attn5<<<dim3(512), 256, 0, stream>>>(Qb, Kb, Vtb, X, Rb, stats);
    ln_norm<<<dim3(1024), 256, 0, stream>>>(Rb, gamma, beta, stats, out);
}

// Round 8
// 198.466 us; speedup vs baseline: 1.1095x; 1.1095x over previous
//
#include <hip/hip_runtime.h>
#include <hip/hip_bf16.h>

// Problem: B=2, S=2048, C=U=1024, H=16, dh=64. I/O FP32.
// cast X->bf16, transpose+cast W->bf16, QKV GEMM (m97-style global_load_lds
// staging; Q pre-scaled by 0.125*log2e), transpose V, flash attention
// (1024-block LPT+XCD grid, dbuf LDS + reg prefetch, S^T/O^T register
// chaining, fixed-offset exp2 softmax, peeled diagonal, fused residual +
// LN-stats), LN apply.

typedef __bf16 bf16_t;
typedef __bf16 bf16x8 __attribute__((ext_vector_type(8)));
typedef __bf16 bf16x4 __attribute__((ext_vector_type(4)));
typedef _Float16 f16_t;
typedef _Float16 f16x4 __attribute__((ext_vector_type(4)));
typedef _Float16 f16x8 __attribute__((ext_vector_type(8)));
typedef float f32x4 __attribute__((ext_vector_type(4)));

constexpr int Bsz = 2;
constexpr int Seq = 2048;
constexpr int Cdim = 1024;   // == U
constexpr int Udim = 1024;
constexpr int Hn = 16;
constexpr int Dh = 64;
constexpr int Mrows = Bsz * Seq;          // 4096
constexpr int PerBatch = Seq * Udim;      // 2^21
constexpr float SCLQ = 0.125f * 1.44269504088896340736f;  // /sqrt(dh) * log2e
constexpr float M0 = 10.0f;               // fixed softmax offset (exp2 domain)

// async global->LDS, 16B per lane; LDS dest = wave-uniform base + lane*16
__device__ __forceinline__ void gload16(const void* g, void* l)
{
    __builtin_amdgcn_global_load_lds(
        (const __attribute__((address_space(1))) void*)g,
        (__attribute__((address_space(3))) void*)l, 16, 0, 0);
}

// ---------------------------------------------------------------- cast X
__global__ __launch_bounds__(256)
void cast_x(const float* __restrict__ X, bf16_t* __restrict__ Xb)
{
    int i = blockIdx.x * 256 + threadIdx.x;     // over float4 groups, 1M total
    float4 v = ((const float4*)X)[i];
    bf16x4 o = { (bf16_t)v.x, (bf16_t)v.y, (bf16_t)v.z, (bf16_t)v.w };
    *(bf16x4*)(Xb + (size_t)i * 4) = o;
}

// ---------------------------------------------------------------- transpose W
__global__ void transpose_w(const float* __restrict__ Wq, const float* __restrict__ Wk,
                            const float* __restrict__ Wv,
                            bf16_t* __restrict__ Tq, bf16_t* __restrict__ Tk,
                            bf16_t* __restrict__ Tv)
{
    int z = blockIdx.z;
    const float* W = (z == 0) ? Wq : (z == 1) ? Wk : Wv;
    bf16_t* T = (z == 0) ? Tq : (z == 1) ? Tk : Tv;
    __shared__ bf16_t t[64][65];
    int x0 = blockIdx.x * 64, y0 = blockIdx.y * 64;
    int tx = threadIdx.x;
    for (int i = threadIdx.y; i < 64; i += 8)
        t[i][tx] = (bf16_t)W[(size_t)(y0 + i) * Cdim + x0 + tx];
    __syncthreads();
    for (int i = threadIdx.y; i < 64; i += 8)
        T[(size_t)(x0 + i) * Cdim + y0 + tx] = t[tx][i];
}

// ---------------------------------------------------------------- QKV GEMM
// m97 structure: 128x128 tile, BK=32, unpadded LDS, global_load_lds width 16.
// Q output (z==0) pre-scaled by SCLQ so attention softmax needs no per-score mul.
__global__ __launch_bounds__(256)
void gemm_qkv(const bf16_t* __restrict__ X,
              const bf16_t* __restrict__ Wt0, const bf16_t* __restrict__ Wt1,
              const bf16_t* __restrict__ Wt2,
              const float* __restrict__ b0, const float* __restrict__ b1,
              const float* __restrict__ b2,
              f16_t* __restrict__ O0, f16_t* __restrict__ O1, f16_t* __restrict__ O2)
{
    int z = blockIdx.z;
    const bf16_t* Wt = (z == 0) ? Wt0 : (z == 1) ? Wt1 : Wt2;
    const float* bias = (z == 0) ? b0 : (z == 1) ? b1 : b2;
    f16_t* Og = (z == 0) ? O0 : (z == 1) ? O1 : O2;
    float scl = (z == 0) ? SCLQ : 1.0f;

    constexpr int Kd = 1024, Nd = 1024;
    __shared__ __align__(16) bf16_t As[128 * 32];
    __shared__ __align__(16) bf16_t Bs[128 * 32];

    int tid = threadIdx.x;
    int wave = tid >> 6, lane = tid & 63, quad = lane >> 4, l16 = lane & 15;
    int wm = (wave & 1) * 64, wn = (wave >> 1) * 64;
    int m0 = blockIdx.y * 128, n0 = blockIdx.x * 128;

    f32x4 acc[4][4] = {};

    int e0 = wave * 512 + lane * 8;
    int r0 = e0 >> 5, c0 = e0 & 31;
    int e1 = e0 + 2048;
    int r1 = e1 >> 5, c1 = e1 & 31;
    const bf16_t* Ag = X + (size_t)m0 * Kd;
    const bf16_t* Bg = Wt + (size_t)n0 * Kd;
    bf16_t* AsW0 = As + wave * 512;
    bf16_t* AsW1 = As + 2048 + wave * 512;
    bf16_t* BsW0 = Bs + wave * 512;
    bf16_t* BsW1 = Bs + 2048 + wave * 512;

    for (int k0 = 0; k0 < Kd; k0 += 32) {
        gload16(Ag + (size_t)r0 * Kd + k0 + c0, AsW0);
        gload16(Ag + (size_t)r1 * Kd + k0 + c1, AsW1);
        gload16(Bg + (size_t)r0 * Kd + k0 + c0, BsW0);
        gload16(Bg + (size_t)r1 * Kd + k0 + c1, BsW1);
        __syncthreads();

        bf16x8 af[4], bfr[4];
#pragma unroll
        for (int i = 0; i < 4; i++)
            af[i] = *(const bf16x8*)&As[(wm + i * 16 + l16) * 32 + quad * 8];
#pragma unroll
        for (int i = 0; i < 4; i++)
            bfr[i] = *(const bf16x8*)&Bs[(wn + i * 16 + l16) * 32 + quad * 8];
#pragma unroll
        for (int mt = 0; mt < 4; mt++)
#pragma unroll
            for (int nt = 0; nt < 4; nt++)
                acc[mt][nt] = __builtin_amdgcn_mfma_f32_16x16x32_bf16(
                    af[mt], bfr[nt], acc[mt][nt], 0, 0, 0);
        __syncthreads();
    }

#pragma unroll
    for (int nt = 0; nt < 4; nt++) {
        int col = n0 + wn + nt * 16 + l16;
        float bv = bias[col];
#pragma unroll
        for (int mt = 0; mt < 4; mt++) {
            int row = m0 + wm + mt * 16 + quad * 4;
#pragma unroll
            for (int r = 0; r < 4; r++)
                Og[(size_t)(row + r) * Nd + col] = (f16_t)((acc[mt][nt][r] + bv) * scl);
        }
    }
}

// ---------------------------------------------------------------- transpose V
// V[4096][1024] f16 -> Vt[b][h][d=64][s=2048] f16
__global__ void transpose_v(const f16_t* __restrict__ V, f16_t* __restrict__ Vt)
{
    int s0 = blockIdx.x * 64;
    int y = blockIdx.y;                 // bh: b = y>>4, h = y&15
    int b = y >> 4, h = y & 15;
    __shared__ f16_t t[64][65];
    int tx = threadIdx.x;
    for (int i = threadIdx.y; i < 64; i += 8)
        t[i][tx] = V[(size_t)(b * Seq + s0 + i) * Udim + h * Dh + tx];
    __syncthreads();
    for (int i = threadIdx.y; i < 64; i += 8)
        Vt[((size_t)y * Dh + i) * Seq + s0 + tx] = t[tx][i];
}

// ---------------------------------------------------------------- attention
// 1024 blocks, one qtile each. LPT order (heavy qtile first) + XCD swizzle
// (same bh -> same id%8). Dbuf LDS + register prefetch. Fixed-offset exp2
// softmax (no running max / no rescale; scale folded into Q). Diagonal
// iteration peeled (mask-free main loop). Deferred l-reduction. Epilogue
// fuses residual + per-batch sum/sumsq stats.
__global__ __launch_bounds__(256)
void attn6(const f16_t* __restrict__ Q, const f16_t* __restrict__ K,
           const f16_t* __restrict__ Vt, const float* __restrict__ X,
           float* __restrict__ R, float* __restrict__ stats)
{
    int id = blockIdx.x;
    int c = id & 7;            // XCD slot
    int r8 = id >> 3;          // [0,128)
    int g = r8 & 3;            // bh-high
    int kk = r8 >> 2;          // [0,32)
    int bh = (g << 3) | c;
    int b = bh >> 4, h = bh & 15;
    int qtile = 31 - kk;       // heavy first in dispatch order

    int tid = threadIdx.x;
    int w = tid >> 6, lane = tid & 63, quad = lane >> 4, l16 = lane & 15;
    size_t bS = (size_t)b * Seq;

    __shared__ f16_t Ks[2][64][72];   // [buf][kv][d]
    __shared__ f16_t Vs[2][64][72];   // [buf][d][kv]

    const f16_t* Kg = K + bS * Udim + h * Dh;
    const f16_t* Vg = Vt + ((size_t)(b * Hn + h)) * Dh * Seq;

    int sr = tid >> 2, sc = (tid & 3) * 16;
    int q0 = qtile * 64 + w * 16;
    int qidx = q0 + l16;

    const f16_t* Qp = Q + (bS + qidx) * Udim + h * Dh;
    f16x8 qf[2];
#pragma unroll
    for (int s = 0; s < 2; s++) qf[s] = *(const f16x8*)(Qp + s * 32 + quad * 8);

    f32x4 Oacc[4] = {};
    float lsum = 0.0f;

    // preload tile 0 into buf 0
    {
        const f16_t* kp = Kg + (size_t)sr * Udim + sc;
        const f16_t* vp = Vg + (size_t)sr * Seq + sc;
        f16x8 k0 = *(const f16x8*)kp;
        f16x8 k1 = *(const f16x8*)(kp + 8);
        f16x8 v0 = *(const f16x8*)vp;
        f16x8 v1 = *(const f16x8*)(vp + 8);
        *(f16x8*)&Ks[0][sr][sc] = k0;
        *(f16x8*)&Ks[0][sr][sc + 8] = k1;
        *(f16x8*)&Vs[0][sr][sc] = v0;
        *(f16x8*)&Vs[0][sr][sc + 8] = v1;
    }
    __syncthreads();

    int buf = 0;
    // ---- main loop: all kv strictly below the diagonal tile, mask-free
    for (int i = 0; i < qtile; i++) {
        int kvn = i * 64 + 64;
        // prefetch next tile (incl. the diagonal tile on the last iter)
        const f16_t* kp = Kg + (size_t)(kvn + sr) * Udim + sc;
        const f16_t* vp = Vg + (size_t)sr * Seq + kvn + sc;
        f16x8 nk0 = *(const f16x8*)kp;
        f16x8 nk1 = *(const f16x8*)(kp + 8);
        f16x8 nv0 = *(const f16x8*)vp;
        f16x8 nv1 = *(const f16x8*)(vp + 8);

        // S^T tiles
        f32x4 st[4];
#pragma unroll
        for (int t = 0; t < 4; t++) {
            f32x4 a = {};
#pragma unroll
            for (int s = 0; s < 2; s++) {
                f16x8 kf = *(const f16x8*)&Ks[buf][t * 16 + l16][s * 32 + quad * 8];
                a = __builtin_amdgcn_mfma_f32_16x16x32_f16(kf, qf[s], a, 0, 0, 0);
            }
            st[t] = a;
        }

        // p = exp2(s' - M0); accumulate lane-local l
        f16x4 pf[4];
#pragma unroll
        for (int t = 0; t < 4; t++)
#pragma unroll
            for (int r = 0; r < 4; r++) {
                float pv = exp2f(st[t][r] - M0);
                lsum += pv;
                pf[t][r] = (f16_t)pv;
            }

        // O^T += V^T . P^T
#pragma unroll
        for (int t = 0; t < 4; t++)
#pragma unroll
            for (int dt = 0; dt < 4; dt++) {
                f16x4 vf = *(const f16x4*)&Vs[buf][dt * 16 + l16][t * 16 + quad * 4];
                Oacc[dt] = __builtin_amdgcn_mfma_f32_16x16x16f16(vf, pf[t], Oacc[dt], 0, 0, 0);
            }

        // commit prefetched tile to the other buffer
        *(f16x8*)&Ks[buf ^ 1][sr][sc] = nk0;
        *(f16x8*)&Ks[buf ^ 1][sr][sc + 8] = nk1;
        *(f16x8*)&Vs[buf ^ 1][sr][sc] = nv0;
        *(f16x8*)&Vs[buf ^ 1][sr][sc + 8] = nv1;
        __syncthreads();
        buf ^= 1;
    }

    // ---- peeled diagonal tile (kv0 = qtile*64), causal-masked, t<=w only
    {
        int kv0 = qtile * 64;
#pragma unroll
        for (int t = 0; t < 4; t++) {
            if (t <= w) {   // wave-uniform: tiles above the diagonal fully masked
                f32x4 a = {};
#pragma unroll
                for (int s = 0; s < 2; s++) {
                    f16x8 kf = *(const f16x8*)&Ks[buf][t * 16 + l16][s * 32 + quad * 8];
                    a = __builtin_amdgcn_mfma_f32_16x16x32_f16(kf, qf[s], a, 0, 0, 0);
                }
                f16x4 pfd;
#pragma unroll
                for (int r = 0; r < 4; r++) {
                    float sv = a[r];
                    if (kv0 + t * 16 + quad * 4 + r > qidx) sv = -1e30f;  // causal
                    float pv = exp2f(sv - M0);
                    lsum += pv;
                    pfd[r] = (f16_t)pv;
                }
#pragma unroll
                for (int dt = 0; dt < 4; dt++) {
                    f16x4 vf = *(const f16x4*)&Vs[buf][dt * 16 + l16][t * 16 + quad * 4];
                    Oacc[dt] = __builtin_amdgcn_mfma_f32_16x16x16f16(vf, pfd, Oacc[dt], 0, 0, 0);
                }
            }
        }
    }

    // deferred l reduction across the 4 quad-groups holding this q row
    lsum += __shfl_xor(lsum, 16);
    lsum += __shfl_xor(lsum, 32);
    float invl = 1.0f / lsum;

    // epilogue: resid = O/l + X ; accumulate stats
    float s_acc = 0.0f, ss_acc = 0.0f;
    const float* Xp = X + (bS + qidx) * Udim + h * Dh;
    float* Rp = R + (bS + qidx) * Udim + h * Dh;
#pragma unroll
    for (int dt = 0; dt < 4; dt++) {
        f32x4 xv = *(const f32x4*)(Xp + dt * 16 + quad * 4);
        f32x4 o = Oacc[dt] * invl + xv;
        *(f32x4*)(Rp + dt * 16 + quad * 4) = o;
#pragma unroll
        for (int r = 0; r < 4; r++) {
            s_acc += o[r];
            ss_acc += o[r] * o[r];
        }
    }

    // block-level stats reduction -> 2 atomics
#pragma unroll
    for (int o = 1; o < 64; o <<= 1) {
        s_acc += __shfl_xor(s_acc, o);
        ss_acc += __shfl_xor(ss_acc, o);
    }
    __shared__ float red[8];
    if (lane == 0) { red[w] = s_acc; red[4 + w] = ss_acc; }
    __syncthreads();
    if (tid == 0) {
        atomicAdd(&stats[b], red[0] + red[1] + red[2] + red[3]);
        atomicAdd(&stats[2 + b], red[4] + red[5] + red[6] + red[7]);
    }
}

// ---------------------------------------------------------------- LN apply
__global__ __launch_bounds__(256)
void ln_norm(const float* __restrict__ R, const float* __restrict__ gamma,
             const float* __restrict__ beta, const float* __restrict__ stats,
             float* __restrict__ out)
{
    constexpr int TOT4 = Bsz * Seq * Udim / 4;   // 1M float4
    constexpr float invN = 1.0f / (float)PerBatch;
    float mu[2], inv[2];
    for (int b = 0; b < 2; b++) {
        float m = stats[b] * invN;
        float var = stats[2 + b] * invN - m * m;
        mu[b] = m;
        inv[b] = rsqrtf(var + 1e-5f);
    }
    for (int i = blockIdx.x * blockDim.x + threadIdx.x; i < TOT4;
         i += gridDim.x * blockDim.x) {
        int f = i * 4;
        int b = f >> 21;
        int su = f & (PerBatch - 1);
        float4 rv = *(const float4*)(R + f);
        float4 g = *(const float4*)(gamma + su);
        float4 be = *(const float4*)(beta + su);
        float4 o;
        o.x = (rv.x - mu[b]) * inv[b] * g.x + be.x;
        o.y = (rv.y - mu[b]) * inv[b] * g.y + be.y;
        o.z = (rv.z - mu[b]) * inv[b] * g.z + be.z;
        o.w = (rv.w - mu[b]) * inv[b] * g.w + be.w;
        *(float4*)(out + f) = o;
    }
}

// ---------------------------------------------------------------- launch
extern "C" void kernel_launch(void* const* d_in, const int* in_sizes, int n_in,
                              void* d_out, int out_size, void* d_ws, size_t ws_size,
                              hipStream_t stream)
{
    const float* X     = (const float*)d_in[0];
    const float* Wq    = (const float*)d_in[1];
    const float* bq    = (const float*)d_in[2];
    const float* Wk    = (const float*)d_in[3];
    const float* bk    = (const float*)d_in[4];
    const float* Wv    = (const float*)d_in[5];
    const float* bv    = (const float*)d_in[6];
    const float* gamma = (const float*)d_in[7];
    const float* beta  = (const float*)d_in[8];
    float* out = (float*)d_out;

    char* ws = (char*)d_ws;
    size_t off = 0;
    auto alloc = [&](size_t bytes) -> void* {
        void* p = ws + off;
        off += (bytes + 255) & ~(size_t)255;
        return p;
    };
    bf16_t* Xb = (bf16_t*)alloc((size_t)Mrows * Cdim * 2);
    bf16_t* Tq = (bf16_t*)alloc((size_t)Cdim * Udim * 2);
    bf16_t* Tk = (bf16_t*)alloc((size_t)Cdim * Udim * 2);
    bf16_t* Tv = (bf16_t*)alloc((size_t)Cdim * Udim * 2);
    f16_t*  Qb = (f16_t*)alloc((size_t)Mrows * Udim * 2);
    f16_t*  Kb = (f16_t*)alloc((size_t)Mrows * Udim * 2);
    f16_t*  Vb = (f16_t*)alloc((size_t)Mrows * Udim * 2);
    f16_t*  Vtb = (f16_t*)alloc((size_t)Mrows * Udim * 2);
    float*  Rb = (float*)alloc((size_t)Mrows * Udim * 4);
    float*  stats = (float*)alloc(4 * sizeof(float));

    hipMemsetAsync(stats, 0, 4 * sizeof(float), stream);
    cast_x<<<dim3(Mrows * Cdim / 4 / 256), 256, 0, stream>>>(X, Xb);
    transpose_w<<<dim3(16, 16, 3), dim3(64, 8), 0, stream>>>(Wq, Wk, Wv, Tq, Tk, Tv);
    gemm_qkv<<<dim3(8, 32, 3), 256, 0, stream>>>(Xb, Tq, Tk, Tv, bq, bk, bv, Qb, Kb, Vb);
    transpose_v<<<dim3(Seq / 64, Bsz * Hn), dim3(64, 8), 0, stream>>>(Vb, Vtb);
    attn6<<<dim3(1024), 256, 0, stream>>>(Qb, Kb, Vtb, X, Rb, stats);
    ln_norm<<<dim3(1024), 256, 0, stream>>>(Rb, gamma, beta, stats, out);
}

// Round 9
// 193.674 us; speedup vs baseline: 1.1370x; 1.0247x over previous
//
#include <hip/hip_runtime.h>
#include <hip/hip_bf16.h>

// Problem: B=2, S=2048, C=U=1024, H=16, dh=64. I/O FP32.
// 4 dispatches: prep (cast X->bf16 + transpose/cast W->bf16 + zero stats),
// QKV GEMM (m97-style staging; Q pre-scaled; V written directly in [b,h,d,s]),
// flash attention (LPT+XCD grid, dbuf LDS, S^T/O^T register chaining,
// fixed-offset exp2 softmax, fused residual+LN-stats), LN apply.

typedef __bf16 bf16_t;
typedef __bf16 bf16x8 __attribute__((ext_vector_type(8)));
typedef __bf16 bf16x4 __attribute__((ext_vector_type(4)));
typedef _Float16 f16_t;
typedef _Float16 f16x4 __attribute__((ext_vector_type(4)));
typedef _Float16 f16x8 __attribute__((ext_vector_type(8)));
typedef float f32x4 __attribute__((ext_vector_type(4)));

constexpr int Bsz = 2;
constexpr int Seq = 2048;
constexpr int Cdim = 1024;   // == U
constexpr int Udim = 1024;
constexpr int Hn = 16;
constexpr int Dh = 64;
constexpr int Mrows = Bsz * Seq;          // 4096
constexpr int PerBatch = Seq * Udim;      // 2^21
constexpr float SCLQ = 0.125f * 1.44269504088896340736f;  // /sqrt(dh) * log2e
constexpr float M0 = 10.0f;               // fixed softmax offset (exp2 domain)

// async global->LDS, 16B per lane; LDS dest = wave-uniform base + lane*16
__device__ __forceinline__ void gload16(const void* g, void* l)
{
    __builtin_amdgcn_global_load_lds(
        (const __attribute__((address_space(1))) void*)g,
        (__attribute__((address_space(3))) void*)l, 16, 0, 0);
}

// ---------------------------------------------------------------- prep
// z<3: transpose+cast W_z 64x64 tile -> Wt[N][K] bf16. z==3: cast X -> bf16
// (and block (0,0) zeroes the stats accumulator).
__global__ __launch_bounds__(256)
void prep(const float* __restrict__ X,
          const float* __restrict__ Wq, const float* __restrict__ Wk,
          const float* __restrict__ Wv,
          bf16_t* __restrict__ Xb,
          bf16_t* __restrict__ Tq, bf16_t* __restrict__ Tk,
          bf16_t* __restrict__ Tv, float* __restrict__ stats)
{
    int z = blockIdx.z;
    int tid = threadIdx.x;
    if (z < 3) {
        const float* W = (z == 0) ? Wq : (z == 1) ? Wk : Wv;
        bf16_t* T = (z == 0) ? Tq : (z == 1) ? Tk : Tv;
        __shared__ bf16_t t[64][65];
        int x0 = blockIdx.x * 64, y0 = blockIdx.y * 64;
        int tx = tid & 63, ty = tid >> 6;
        for (int i = ty; i < 64; i += 4)
            t[i][tx] = (bf16_t)W[(size_t)(y0 + i) * Cdim + x0 + tx];
        __syncthreads();
        for (int i = ty; i < 64; i += 4)
            T[(size_t)(x0 + i) * Cdim + y0 + tx] = t[tx][i];
    } else {
        int bi = blockIdx.y * 16 + blockIdx.x;          // 0..255
        if (bi == 0 && tid < 4) stats[tid] = 0.0f;
        const float4* Xv = (const float4*)X;
#pragma unroll
        for (int k = 0; k < 16; k++) {
            int i = bi * 4096 + k * 256 + tid;          // 1M float4 total
            float4 v = Xv[i];
            bf16x4 o = { (bf16_t)v.x, (bf16_t)v.y, (bf16_t)v.z, (bf16_t)v.w };
            *(bf16x4*)(Xb + (size_t)i * 4) = o;
        }
    }
}

// ---------------------------------------------------------------- QKV GEMM
// m97 structure: 128x128 tile, BK=32, unpadded LDS, global_load_lds width 16.
// z==0: Q, pre-scaled by SCLQ. z==1: K, normal layout. z==2: V written
// directly transposed to Vt[b][h][d][s] (4 s-contiguous f16 per store).
__global__ __launch_bounds__(256)
void gemm_qkv(const bf16_t* __restrict__ X,
              const bf16_t* __restrict__ Wt0, const bf16_t* __restrict__ Wt1,
              const bf16_t* __restrict__ Wt2,
              const float* __restrict__ b0, const float* __restrict__ b1,
              const float* __restrict__ b2,
              f16_t* __restrict__ O0, f16_t* __restrict__ O1, f16_t* __restrict__ O2v)
{
    int z = blockIdx.z;
    const bf16_t* Wt = (z == 0) ? Wt0 : (z == 1) ? Wt1 : Wt2;
    const float* bias = (z == 0) ? b0 : (z == 1) ? b1 : b2;
    float scl = (z == 0) ? SCLQ : 1.0f;

    constexpr int Kd = 1024, Nd = 1024;
    __shared__ __align__(16) bf16_t As[128 * 32];
    __shared__ __align__(16) bf16_t Bs[128 * 32];

    int tid = threadIdx.x;
    int wave = tid >> 6, lane = tid & 63, quad = lane >> 4, l16 = lane & 15;
    int wm = (wave & 1) * 64, wn = (wave >> 1) * 64;
    int m0 = blockIdx.y * 128, n0 = blockIdx.x * 128;

    f32x4 acc[4][4] = {};

    int e0 = wave * 512 + lane * 8;
    int r0 = e0 >> 5, c0 = e0 & 31;
    int e1 = e0 + 2048;
    int r1 = e1 >> 5, c1 = e1 & 31;
    const bf16_t* Ag = X + (size_t)m0 * Kd;
    const bf16_t* Bg = Wt + (size_t)n0 * Kd;
    bf16_t* AsW0 = As + wave * 512;
    bf16_t* AsW1 = As + 2048 + wave * 512;
    bf16_t* BsW0 = Bs + wave * 512;
    bf16_t* BsW1 = Bs + 2048 + wave * 512;

    for (int k0 = 0; k0 < Kd; k0 += 32) {
        gload16(Ag + (size_t)r0 * Kd + k0 + c0, AsW0);
        gload16(Ag + (size_t)r1 * Kd + k0 + c1, AsW1);
        gload16(Bg + (size_t)r0 * Kd + k0 + c0, BsW0);
        gload16(Bg + (size_t)r1 * Kd + k0 + c1, BsW1);
        __syncthreads();

        bf16x8 af[4], bfr[4];
#pragma unroll
        for (int i = 0; i < 4; i++)
            af[i] = *(const bf16x8*)&As[(wm + i * 16 + l16) * 32 + quad * 8];
#pragma unroll
        for (int i = 0; i < 4; i++)
            bfr[i] = *(const bf16x8*)&Bs[(wn + i * 16 + l16) * 32 + quad * 8];
#pragma unroll
        for (int mt = 0; mt < 4; mt++)
#pragma unroll
            for (int nt = 0; nt < 4; nt++)
                acc[mt][nt] = __builtin_amdgcn_mfma_f32_16x16x32_bf16(
                    af[mt], bfr[nt], acc[mt][nt], 0, 0, 0);
        __syncthreads();
    }

    if (z < 2) {
        f16_t* Og = (z == 0) ? O0 : O1;
#pragma unroll
        for (int nt = 0; nt < 4; nt++) {
            int col = n0 + wn + nt * 16 + l16;
            float bv = bias[col];
#pragma unroll
            for (int mt = 0; mt < 4; mt++) {
                int row = m0 + wm + mt * 16 + quad * 4;
#pragma unroll
                for (int r = 0; r < 4; r++)
                    Og[(size_t)(row + r) * Nd + col] = (f16_t)((acc[mt][nt][r] + bv) * scl);
            }
        }
    } else {
        // V -> Vt[b][h][d][s]: b=m0>>11 (const per block), h=col>>6, d=col&63,
        // s=row&2047; the 4 r-values are s-contiguous -> f16x4 store.
        int bb = m0 >> 11;
#pragma unroll
        for (int nt = 0; nt < 4; nt++) {
            int col = n0 + wn + nt * 16 + l16;
            float bv = bias[col];
            int h = col >> 6, d = col & 63;
            f16_t* vbase = O2v + (((size_t)(bb * Hn + h) * Dh + d) << 11);
#pragma unroll
            for (int mt = 0; mt < 4; mt++) {
                int row = m0 + wm + mt * 16 + quad * 4;
                int s = row & (Seq - 1);
                f16x4 pk;
#pragma unroll
                for (int r = 0; r < 4; r++) pk[r] = (f16_t)(acc[mt][nt][r] + bv);
                *(f16x4*)(vbase + s) = pk;
            }
        }
    }
}

// ---------------------------------------------------------------- attention
// 1024 blocks, one qtile each. LPT order + XCD swizzle. Dbuf LDS + register
// prefetch. Fixed-offset exp2 softmax (scale folded into Q). Peeled diagonal.
// Epilogue fuses residual + per-batch sum/sumsq stats.
__global__ __launch_bounds__(256)
void attn6(const f16_t* __restrict__ Q, const f16_t* __restrict__ K,
           const f16_t* __restrict__ Vt, const float* __restrict__ X,
           float* __restrict__ R, float* __restrict__ stats)
{
    int id = blockIdx.x;
    int c = id & 7;            // XCD slot
    int r8 = id >> 3;          // [0,128)
    int g = r8 & 3;            // bh-high
    int kk = r8 >> 2;          // [0,32)
    int bh = (g << 3) | c;
    int b = bh >> 4, h = bh & 15;
    int qtile = 31 - kk;       // heavy first in dispatch order

    int tid = threadIdx.x;
    int w = tid >> 6, lane = tid & 63, quad = lane >> 4, l16 = lane & 15;
    size_t bS = (size_t)b * Seq;

    __shared__ f16_t Ks[2][64][72];   // [buf][kv][d]
    __shared__ f16_t Vs[2][64][72];   // [buf][d][kv]

    const f16_t* Kg = K + bS * Udim + h * Dh;
    const f16_t* Vg = Vt + ((size_t)(b * Hn + h)) * Dh * Seq;

    int sr = tid >> 2, sc = (tid & 3) * 16;
    int q0 = qtile * 64 + w * 16;
    int qidx = q0 + l16;

    const f16_t* Qp = Q + (bS + qidx) * Udim + h * Dh;
    f16x8 qf[2];
#pragma unroll
    for (int s = 0; s < 2; s++) qf[s] = *(const f16x8*)(Qp + s * 32 + quad * 8);

    f32x4 Oacc[4] = {};
    float lsum = 0.0f;

    // preload tile 0 into buf 0
    {
        const f16_t* kp = Kg + (size_t)sr * Udim + sc;
        const f16_t* vp = Vg + (size_t)sr * Seq + sc;
        f16x8 k0 = *(const f16x8*)kp;
        f16x8 k1 = *(const f16x8*)(kp + 8);
        f16x8 v0 = *(const f16x8*)vp;
        f16x8 v1 = *(const f16x8*)(vp + 8);
        *(f16x8*)&Ks[0][sr][sc] = k0;
        *(f16x8*)&Ks[0][sr][sc + 8] = k1;
        *(f16x8*)&Vs[0][sr][sc] = v0;
        *(f16x8*)&Vs[0][sr][sc + 8] = v1;
    }
    __syncthreads();

    int buf = 0;
    // ---- main loop: all kv strictly below the diagonal tile, mask-free
    for (int i = 0; i < qtile; i++) {
        int kvn = i * 64 + 64;
        const f16_t* kp = Kg + (size_t)(kvn + sr) * Udim + sc;
        const f16_t* vp = Vg + (size_t)sr * Seq + kvn + sc;
        f16x8 nk0 = *(const f16x8*)kp;
        f16x8 nk1 = *(const f16x8*)(kp + 8);
        f16x8 nv0 = *(const f16x8*)vp;
        f16x8 nv1 = *(const f16x8*)(vp + 8);

        f32x4 st[4];
#pragma unroll
        for (int t = 0; t < 4; t++) {
            f32x4 a = {};
#pragma unroll
            for (int s = 0; s < 2; s++) {
                f16x8 kf = *(const f16x8*)&Ks[buf][t * 16 + l16][s * 32 + quad * 8];
                a = __builtin_amdgcn_mfma_f32_16x16x32_f16(kf, qf[s], a, 0, 0, 0);
            }
            st[t] = a;
        }

        f16x4 pf[4];
#pragma unroll
        for (int t = 0; t < 4; t++)
#pragma unroll
            for (int r = 0; r < 4; r++) {
                float pv = exp2f(st[t][r] - M0);
                lsum += pv;
                pf[t][r] = (f16_t)pv;
            }

#pragma unroll
        for (int t = 0; t < 4; t++)
#pragma unroll
            for (int dt = 0; dt < 4; dt++) {
                f16x4 vf = *(const f16x4*)&Vs[buf][dt * 16 + l16][t * 16 + quad * 4];
                Oacc[dt] = __builtin_amdgcn_mfma_f32_16x16x16f16(vf, pf[t], Oacc[dt], 0, 0, 0);
            }

        *(f16x8*)&Ks[buf ^ 1][sr][sc] = nk0;
        *(f16x8*)&Ks[buf ^ 1][sr][sc + 8] = nk1;
        *(f16x8*)&Vs[buf ^ 1][sr][sc] = nv0;
        *(f16x8*)&Vs[buf ^ 1][sr][sc + 8] = nv1;
        __syncthreads();
        buf ^= 1;
    }

    // ---- peeled diagonal tile, causal-masked, t<=w only (wave-uniform)
    {
        int kv0 = qtile * 64;
#pragma unroll
        for (int t = 0; t < 4; t++) {
            if (t <= w) {
                f32x4 a = {};
#pragma unroll
                for (int s = 0; s < 2; s++) {
                    f16x8 kf = *(const f16x8*)&Ks[buf][t * 16 + l16][s * 32 + quad * 8];
                    a = __builtin_amdgcn_mfma_f32_16x16x32_f16(kf, qf[s], a, 0, 0, 0);
                }
                f16x4 pfd;
#pragma unroll
                for (int r = 0; r < 4; r++) {
                    float sv = a[r];
                    if (kv0 + t * 16 + quad * 4 + r > qidx) sv = -1e30f;  // causal
                    float pv = exp2f(sv - M0);
                    lsum += pv;
                    pfd[r] = (f16_t)pv;
                }
#pragma unroll
                for (int dt = 0; dt < 4; dt++) {
                    f16x4 vf = *(const f16x4*)&Vs[buf][dt * 16 + l16][t * 16 + quad * 4];
                    Oacc[dt] = __builtin_amdgcn_mfma_f32_16x16x16f16(vf, pfd, Oacc[dt], 0, 0, 0);
                }
            }
        }
    }

    lsum += __shfl_xor(lsum, 16);
    lsum += __shfl_xor(lsum, 32);
    float invl = 1.0f / lsum;

    float s_acc = 0.0f, ss_acc = 0.0f;
    const float* Xp = X + (bS + qidx) * Udim + h * Dh;
    float* Rp = R + (bS + qidx) * Udim + h * Dh;
#pragma unroll
    for (int dt = 0; dt < 4; dt++) {
        f32x4 xv = *(const f32x4*)(Xp + dt * 16 + quad * 4);
        f32x4 o = Oacc[dt] * invl + xv;
        *(f32x4*)(Rp + dt * 16 + quad * 4) = o;
#pragma unroll
        for (int r = 0; r < 4; r++) {
            s_acc += o[r];
            ss_acc += o[r] * o[r];
        }
    }

#pragma unroll
    for (int o = 1; o < 64; o <<= 1) {
        s_acc += __shfl_xor(s_acc, o);
        ss_acc += __shfl_xor(ss_acc, o);
    }
    __shared__ float red[8];
    if (lane == 0) { red[w] = s_acc; red[4 + w] = ss_acc; }
    __syncthreads();
    if (tid == 0) {
        atomicAdd(&stats[b], red[0] + red[1] + red[2] + red[3]);
        atomicAdd(&stats[2 + b], red[4] + red[5] + red[6] + red[7]);
    }
}

// ---------------------------------------------------------------- LN apply
__global__ __launch_bounds__(256)
void ln_norm(const float* __restrict__ R, const float* __restrict__ gamma,
             const float* __restrict__ beta, const float* __restrict__ stats,
             float* __restrict__ out)
{
    constexpr int TOT4 = Bsz * Seq * Udim / 4;   // 1M float4
    constexpr float invN = 1.0f / (float)PerBatch;
    float mu[2], inv[2];
    for (int b = 0; b < 2; b++) {
        float m = stats[b] * invN;
        float var = stats[2 + b] * invN - m * m;
        mu[b] = m;
        inv[b] = rsqrtf(var + 1e-5f);
    }
    for (int i = blockIdx.x * blockDim.x + threadIdx.x; i < TOT4;
         i += gridDim.x * blockDim.x) {
        int f = i * 4;
        int b = f >> 21;
        int su = f & (PerBatch - 1);
        float4 rv = *(const float4*)(R + f);
        float4 g = *(const float4*)(gamma + su);
        float4 be = *(const float4*)(beta + su);
        float4 o;
        o.x = (rv.x - mu[b]) * inv[b] * g.x + be.x;
        o.y = (rv.y - mu[b]) * inv[b] * g.y + be.y;
        o.z = (rv.z - mu[b]) * inv[b] * g.z + be.z;
        o.w = (rv.w - mu[b]) * inv[b] * g.w + be.w;
        *(float4*)(out + f) = o;
    }
}

// ---------------------------------------------------------------- launch
extern "C" void kernel_launch(void* const* d_in, const int* in_sizes, int n_in,
                              void* d_out, int out_size, void* d_ws, size_t ws_size,
                              hipStream_t stream)
{
    const float* X     = (const float*)d_in[0];
    const float* Wq    = (const float*)d_in[1];
    const float* bq    = (const float*)d_in[2];
    const float* Wk    = (const float*)d_in[3];
    const float* bk    = (const float*)d_in[4];
    const float* Wv    = (const float*)d_in[5];
    const float* bv    = (const float*)d_in[6];
    const float* gamma = (const float*)d_in[7];
    const float* beta  = (const float*)d_in[8];
    float* out = (float*)d_out;

    char* ws = (char*)d_ws;
    size_t off = 0;
    auto alloc = [&](size_t bytes) -> void* {
        void* p = ws + off;
        off += (bytes + 255) & ~(size_t)255;
        return p;
    };
    bf16_t* Xb = (bf16_t*)alloc((size_t)Mrows * Cdim * 2);
    bf16_t* Tq = (bf16_t*)alloc((size_t)Cdim * Udim * 2);
    bf16_t* Tk = (bf16_t*)alloc((size_t)Cdim * Udim * 2);
    bf16_t* Tv = (bf16_t*)alloc((size_t)Cdim * Udim * 2);
    f16_t*  Qb = (f16_t*)alloc((size_t)Mrows * Udim * 2);
    f16_t*  Kb = (f16_t*)alloc((size_t)Mrows * Udim * 2);
    f16_t*  Vtb = (f16_t*)alloc((size_t)Mrows * Udim * 2);
    float*  Rb = (float*)alloc((size_t)Mrows * Udim * 4);
    float*  stats = (float*)alloc(4 * sizeof(float));

    prep<<<dim3(16, 16, 4), 256, 0, stream>>>(X, Wq, Wk, Wv, Xb, Tq, Tk, Tv, stats);
    gemm_qkv<<<dim3(8, 32, 3), 256, 0, stream>>>(Xb, Tq, Tk, Tv, bq, bk, bv, Qb, Kb, Vtb);
    attn6<<<dim3(1024), 256, 0, stream>>>(Qb, Kb, Vtb, X, Rb, stats);
    ln_norm<<<dim3(1024), 256, 0, stream>>>(Rb, gamma, beta, stats, out);
}

// Round 11
// 187.815 us; speedup vs baseline: 1.1724x; 1.0312x over previous
//
#include <hip/hip_runtime.h>
#include <hip/hip_bf16.h>

// Problem: B=2, S=2048, C=U=1024, H=16, dh=64. I/O FP32.
// 4 dispatches: prep (cast X->bf16 + transpose/cast W->bf16 + zero stats),
// QKV GEMM (m97-style staging; Q pre-scaled; V written directly in [b,h,d,s]),
// flash attention (LPT+XCD grid, dbuf LDS, S^T/O^T register chaining,
// offset-free exp2 softmax, fused residual(bf16)+LN-stats), LN apply.

typedef __bf16 bf16_t;
typedef __bf16 bf16x8 __attribute__((ext_vector_type(8)));
typedef __bf16 bf16x4 __attribute__((ext_vector_type(4)));
typedef _Float16 f16_t;
typedef _Float16 f16x2 __attribute__((ext_vector_type(2)));
typedef _Float16 f16x4 __attribute__((ext_vector_type(4)));
typedef _Float16 f16x8 __attribute__((ext_vector_type(8)));
typedef float f32x4 __attribute__((ext_vector_type(4)));

constexpr int Bsz = 2;
constexpr int Seq = 2048;
constexpr int Cdim = 1024;   // == U
constexpr int Udim = 1024;
constexpr int Hn = 16;
constexpr int Dh = 64;
constexpr int Mrows = Bsz * Seq;          // 4096
constexpr int PerBatch = Seq * Udim;      // 2^21
constexpr float SCLQ = 0.125f * 1.44269504088896340736f;  // /sqrt(dh) * log2e

// async global->LDS, 16B per lane; LDS dest = wave-uniform base + lane*16
__device__ __forceinline__ void gload16(const void* g, void* l)
{
    __builtin_amdgcn_global_load_lds(
        (const __attribute__((address_space(1))) void*)g,
        (__attribute__((address_space(3))) void*)l, 16, 0, 0);
}

// pack two f32 -> f16x2 via v_cvt_pkrtz (returns __fp16x2; bit-identical)
__device__ __forceinline__ f16x2 pkrtz(float a, float b)
{
    return __builtin_bit_cast(f16x2, __builtin_amdgcn_cvt_pkrtz(a, b));
}

// ---------------------------------------------------------------- prep
__global__ __launch_bounds__(256)
void prep(const float* __restrict__ X,
          const float* __restrict__ Wq, const float* __restrict__ Wk,
          const float* __restrict__ Wv,
          bf16_t* __restrict__ Xb,
          bf16_t* __restrict__ Tq, bf16_t* __restrict__ Tk,
          bf16_t* __restrict__ Tv, float* __restrict__ stats)
{
    int z = blockIdx.z;
    int tid = threadIdx.x;
    if (z < 3) {
        const float* W = (z == 0) ? Wq : (z == 1) ? Wk : Wv;
        bf16_t* T = (z == 0) ? Tq : (z == 1) ? Tk : Tv;
        __shared__ bf16_t t[64][65];
        int x0 = blockIdx.x * 64, y0 = blockIdx.y * 64;
        int tx = tid & 63, ty = tid >> 6;
        for (int i = ty; i < 64; i += 4)
            t[i][tx] = (bf16_t)W[(size_t)(y0 + i) * Cdim + x0 + tx];
        __syncthreads();
        for (int i = ty; i < 64; i += 4)
            T[(size_t)(x0 + i) * Cdim + y0 + tx] = t[tx][i];
    } else {
        int bi = blockIdx.y * 16 + blockIdx.x;          // 0..255
        if (bi == 0 && tid < 4) stats[tid] = 0.0f;
        const float4* Xv = (const float4*)X;
#pragma unroll
        for (int k = 0; k < 16; k++) {
            int i = bi * 4096 + k * 256 + tid;          // 1M float4 total
            float4 v = Xv[i];
            bf16x4 o = { (bf16_t)v.x, (bf16_t)v.y, (bf16_t)v.z, (bf16_t)v.w };
            *(bf16x4*)(Xb + (size_t)i * 4) = o;
        }
    }
}

// ---------------------------------------------------------------- QKV GEMM
// m97 structure: 128x128 tile, BK=32, unpadded LDS, global_load_lds width 16.
// z==0: Q pre-scaled by SCLQ. z==1: K. z==2: V -> Vt[b][h][d][s].
__global__ __launch_bounds__(256)
void gemm_qkv(const bf16_t* __restrict__ X,
              const bf16_t* __restrict__ Wt0, const bf16_t* __restrict__ Wt1,
              const bf16_t* __restrict__ Wt2,
              const float* __restrict__ b0, const float* __restrict__ b1,
              const float* __restrict__ b2,
              f16_t* __restrict__ O0, f16_t* __restrict__ O1, f16_t* __restrict__ O2v)
{
    int z = blockIdx.z;
    const bf16_t* Wt = (z == 0) ? Wt0 : (z == 1) ? Wt1 : Wt2;
    const float* bias = (z == 0) ? b0 : (z == 1) ? b1 : b2;
    float scl = (z == 0) ? SCLQ : 1.0f;

    constexpr int Kd = 1024, Nd = 1024;
    __shared__ __align__(16) bf16_t As[128 * 32];
    __shared__ __align__(16) bf16_t Bs[128 * 32];

    int tid = threadIdx.x;
    int wave = tid >> 6, lane = tid & 63, quad = lane >> 4, l16 = lane & 15;
    int wm = (wave & 1) * 64, wn = (wave >> 1) * 64;
    int m0 = blockIdx.y * 128, n0 = blockIdx.x * 128;

    f32x4 acc[4][4] = {};

    int e0 = wave * 512 + lane * 8;
    int r0 = e0 >> 5, c0 = e0 & 31;
    int e1 = e0 + 2048;
    int r1 = e1 >> 5, c1 = e1 & 31;
    const bf16_t* Ag = X + (size_t)m0 * Kd;
    const bf16_t* Bg = Wt + (size_t)n0 * Kd;
    bf16_t* AsW0 = As + wave * 512;
    bf16_t* AsW1 = As + 2048 + wave * 512;
    bf16_t* BsW0 = Bs + wave * 512;
    bf16_t* BsW1 = Bs + 2048 + wave * 512;

    for (int k0 = 0; k0 < Kd; k0 += 32) {
        gload16(Ag + (size_t)r0 * Kd + k0 + c0, AsW0);
        gload16(Ag + (size_t)r1 * Kd + k0 + c1, AsW1);
        gload16(Bg + (size_t)r0 * Kd + k0 + c0, BsW0);
        gload16(Bg + (size_t)r1 * Kd + k0 + c1, BsW1);
        __syncthreads();

        bf16x8 af[4], bfr[4];
#pragma unroll
        for (int i = 0; i < 4; i++)
            af[i] = *(const bf16x8*)&As[(wm + i * 16 + l16) * 32 + quad * 8];
#pragma unroll
        for (int i = 0; i < 4; i++)
            bfr[i] = *(const bf16x8*)&Bs[(wn + i * 16 + l16) * 32 + quad * 8];
#pragma unroll
        for (int mt = 0; mt < 4; mt++)
#pragma unroll
            for (int nt = 0; nt < 4; nt++)
                acc[mt][nt] = __builtin_amdgcn_mfma_f32_16x16x32_bf16(
                    af[mt], bfr[nt], acc[mt][nt], 0, 0, 0);
        __syncthreads();
    }

    if (z < 2) {
        f16_t* Og = (z == 0) ? O0 : O1;
#pragma unroll
        for (int nt = 0; nt < 4; nt++) {
            int col = n0 + wn + nt * 16 + l16;
            float bv = bias[col];
#pragma unroll
            for (int mt = 0; mt < 4; mt++) {
                int row = m0 + wm + mt * 16 + quad * 4;
#pragma unroll
                for (int r = 0; r < 4; r++)
                    Og[(size_t)(row + r) * Nd + col] = (f16_t)((acc[mt][nt][r] + bv) * scl);
            }
        }
    } else {
        int bb = m0 >> 11;
#pragma unroll
        for (int nt = 0; nt < 4; nt++) {
            int col = n0 + wn + nt * 16 + l16;
            float bv = bias[col];
            int h = col >> 6, d = col & 63;
            f16_t* vbase = O2v + (((size_t)(bb * Hn + h) * Dh + d) << 11);
#pragma unroll
            for (int mt = 0; mt < 4; mt++) {
                int row = m0 + wm + mt * 16 + quad * 4;
                int s = row & (Seq - 1);
                f16x4 pk;
#pragma unroll
                for (int r = 0; r < 4; r++) pk[r] = (f16_t)(acc[mt][nt][r] + bv);
                *(f16x4*)(vbase + s) = pk;
            }
        }
    }
}

// ---------------------------------------------------------------- attention
// 1024 blocks, one qtile each. LPT + XCD swizzle. Dbuf LDS + reg prefetch.
// Offset-free exp2 softmax (scale folded into Q; constant factor cancels in
// O/l). Peeled diagonal. Epilogue: resid bf16 + per-batch sum/sumsq stats.
__global__ __launch_bounds__(256)
void attn7(const f16_t* __restrict__ Q, const f16_t* __restrict__ K,
           const f16_t* __restrict__ Vt, const float* __restrict__ X,
           bf16_t* __restrict__ R, float* __restrict__ stats)
{
    int id = blockIdx.x;
    int c = id & 7;            // XCD slot
    int r8 = id >> 3;
    int g = r8 & 3;
    int kk = r8 >> 2;
    int bh = (g << 3) | c;
    int b = bh >> 4, h = bh & 15;
    int qtile = 31 - kk;       // heavy first

    int tid = threadIdx.x;
    int w = tid >> 6, lane = tid & 63, quad = lane >> 4, l16 = lane & 15;
    size_t bS = (size_t)b * Seq;

    __shared__ f16_t Ks[2][64][72];   // [buf][kv][d]
    __shared__ f16_t Vs[2][64][72];   // [buf][d][kv]

    const f16_t* Kg = K + bS * Udim + h * Dh;
    const f16_t* Vg = Vt + ((size_t)(b * Hn + h)) * Dh * Seq;

    int sr = tid >> 2, sc = (tid & 3) * 16;
    int q0 = qtile * 64 + w * 16;
    int qidx = q0 + l16;

    const f16_t* Qp = Q + (bS + qidx) * Udim + h * Dh;
    f16x8 qf[2];
#pragma unroll
    for (int s = 0; s < 2; s++) qf[s] = *(const f16x8*)(Qp + s * 32 + quad * 8);

    f32x4 Oacc[4] = {};
    float lsum = 0.0f;

    // running staging pointers
    const f16_t* kp = Kg + (size_t)sr * Udim + sc;
    const f16_t* vp = Vg + (size_t)sr * Seq + sc;

    // preload tile 0 into buf 0
    {
        f16x8 k0 = *(const f16x8*)kp;
        f16x8 k1 = *(const f16x8*)(kp + 8);
        f16x8 v0 = *(const f16x8*)vp;
        f16x8 v1 = *(const f16x8*)(vp + 8);
        *(f16x8*)&Ks[0][sr][sc] = k0;
        *(f16x8*)&Ks[0][sr][sc + 8] = k1;
        *(f16x8*)&Vs[0][sr][sc] = v0;
        *(f16x8*)&Vs[0][sr][sc + 8] = v1;
        kp += (size_t)64 * Udim;
        vp += 64;
    }
    __syncthreads();

    int buf = 0;
    // ---- main loop: all kv strictly below the diagonal tile, mask-free
    for (int i = 0; i < qtile; i++) {
        f16x8 nk0 = *(const f16x8*)kp;
        f16x8 nk1 = *(const f16x8*)(kp + 8);
        f16x8 nv0 = *(const f16x8*)vp;
        f16x8 nv1 = *(const f16x8*)(vp + 8);
        kp += (size_t)64 * Udim;
        vp += 64;

        f32x4 st[4];
#pragma unroll
        for (int t = 0; t < 4; t++) {
            f32x4 a = {};
#pragma unroll
            for (int s = 0; s < 2; s++) {
                f16x8 kf = *(const f16x8*)&Ks[buf][t * 16 + l16][s * 32 + quad * 8];
                a = __builtin_amdgcn_mfma_f32_16x16x32_f16(kf, qf[s], a, 0, 0, 0);
            }
            st[t] = a;
        }

        f16x4 pf[4];
#pragma unroll
        for (int t = 0; t < 4; t++) {
            float p0 = exp2f(st[t][0]);
            float p1 = exp2f(st[t][1]);
            float p2 = exp2f(st[t][2]);
            float p3 = exp2f(st[t][3]);
            lsum += (p0 + p1) + (p2 + p3);
            f16x2 lo = pkrtz(p0, p1);
            f16x2 hi = pkrtz(p2, p3);
            pf[t][0] = lo[0]; pf[t][1] = lo[1];
            pf[t][2] = hi[0]; pf[t][3] = hi[1];
        }

#pragma unroll
        for (int t = 0; t < 4; t++)
#pragma unroll
            for (int dt = 0; dt < 4; dt++) {
                f16x4 vf = *(const f16x4*)&Vs[buf][dt * 16 + l16][t * 16 + quad * 4];
                Oacc[dt] = __builtin_amdgcn_mfma_f32_16x16x16f16(vf, pf[t], Oacc[dt], 0, 0, 0);
            }

        *(f16x8*)&Ks[buf ^ 1][sr][sc] = nk0;
        *(f16x8*)&Ks[buf ^ 1][sr][sc + 8] = nk1;
        *(f16x8*)&Vs[buf ^ 1][sr][sc] = nv0;
        *(f16x8*)&Vs[buf ^ 1][sr][sc + 8] = nv1;
        __syncthreads();
        buf ^= 1;
    }

    // ---- peeled diagonal tile, causal-masked, t<=w only (wave-uniform)
    {
        int kv0 = qtile * 64;
#pragma unroll
        for (int t = 0; t < 4; t++) {
            if (t <= w) {
                f32x4 a = {};
#pragma unroll
                for (int s = 0; s < 2; s++) {
                    f16x8 kf = *(const f16x8*)&Ks[buf][t * 16 + l16][s * 32 + quad * 8];
                    a = __builtin_amdgcn_mfma_f32_16x16x32_f16(kf, qf[s], a, 0, 0, 0);
                }
                f16x4 pfd;
#pragma unroll
                for (int r = 0; r < 4; r++) {
                    float sv = a[r];
                    if (kv0 + t * 16 + quad * 4 + r > qidx) sv = -1e30f;  // causal
                    float pv = exp2f(sv);
                    lsum += pv;
                    pfd[r] = (f16_t)pv;
                }
#pragma unroll
                for (int dt = 0; dt < 4; dt++) {
                    f16x4 vf = *(const f16x4*)&Vs[buf][dt * 16 + l16][t * 16 + quad * 4];
                    Oacc[dt] = __builtin_amdgcn_mfma_f32_16x16x16f16(vf, pfd, Oacc[dt], 0, 0, 0);
                }
            }
        }
    }

    lsum += __shfl_xor(lsum, 16);
    lsum += __shfl_xor(lsum, 32);
    float invl = 1.0f / lsum;

    float s_acc = 0.0f, ss_acc = 0.0f;
    const float* Xp = X + (bS + qidx) * Udim + h * Dh;
    bf16_t* Rp = R + (bS + qidx) * Udim + h * Dh;
#pragma unroll
    for (int dt = 0; dt < 4; dt++) {
        f32x4 xv = *(const f32x4*)(Xp + dt * 16 + quad * 4);
        f32x4 o = Oacc[dt] * invl + xv;
        bf16x4 ob;
#pragma unroll
        for (int r = 0; r < 4; r++) {
            ob[r] = (bf16_t)o[r];
            s_acc += o[r];
            ss_acc += o[r] * o[r];
        }
        *(bf16x4*)(Rp + dt * 16 + quad * 4) = ob;
    }

#pragma unroll
    for (int o = 1; o < 64; o <<= 1) {
        s_acc += __shfl_xor(s_acc, o);
        ss_acc += __shfl_xor(ss_acc, o);
    }
    __shared__ float red[8];
    if (lane == 0) { red[w] = s_acc; red[4 + w] = ss_acc; }
    __syncthreads();
    if (tid == 0) {
        atomicAdd(&stats[b], red[0] + red[1] + red[2] + red[3]);
        atomicAdd(&stats[2 + b], red[4] + red[5] + red[6] + red[7]);
    }
}

// ---------------------------------------------------------------- LN apply
__global__ __launch_bounds__(256)
void ln_norm(const bf16_t* __restrict__ R, const float* __restrict__ gamma,
             const float* __restrict__ beta, const float* __restrict__ stats,
             float* __restrict__ out)
{
    constexpr float invN = 1.0f / (float)PerBatch;
    float mu[2], inv[2];
#pragma unroll
    for (int b = 0; b < 2; b++) {
        float m = stats[b] * invN;
        float var = stats[2 + b] * invN - m * m;
        mu[b] = m;
        inv[b] = rsqrtf(var + 1e-5f);
    }
    int i = blockIdx.x * 256 + threadIdx.x;      // over 8-elem groups, 512K
    int f = i * 8;
    int b = f >> 21;
    int su = f & (PerBatch - 1);
    bf16x8 rv = *(const bf16x8*)(R + f);
    float4 g0 = *(const float4*)(gamma + su);
    float4 g1 = *(const float4*)(gamma + su + 4);
    float4 be0 = *(const float4*)(beta + su);
    float4 be1 = *(const float4*)(beta + su + 4);
    float4 o0, o1;
    o0.x = ((float)rv[0] - mu[b]) * inv[b] * g0.x + be0.x;
    o0.y = ((float)rv[1] - mu[b]) * inv[b] * g0.y + be0.y;
    o0.z = ((float)rv[2] - mu[b]) * inv[b] * g0.z + be0.z;
    o0.w = ((float)rv[3] - mu[b]) * inv[b] * g0.w + be0.w;
    o1.x = ((float)rv[4] - mu[b]) * inv[b] * g1.x + be1.x;
    o1.y = ((float)rv[5] - mu[b]) * inv[b] * g1.y + be1.y;
    o1.z = ((float)rv[6] - mu[b]) * inv[b] * g1.z + be1.z;
    o1.w = ((float)rv[7] - mu[b]) * inv[b] * g1.w + be1.w;
    *(float4*)(out + f) = o0;
    *(float4*)(out + f + 4) = o1;
}

// ---------------------------------------------------------------- launch
extern "C" void kernel_launch(void* const* d_in, const int* in_sizes, int n_in,
                              void* d_out, int out_size, void* d_ws, size_t ws_size,
                              hipStream_t stream)
{
    const float* X     = (const float*)d_in[0];
    const float* Wq    = (const float*)d_in[1];
    const float* bq    = (const float*)d_in[2];
    const float* Wk    = (const float*)d_in[3];
    const float* bk    = (const float*)d_in[4];
    const float* Wv    = (const float*)d_in[5];
    const float* bv    = (const float*)d_in[6];
    const float* gamma = (const float*)d_in[7];
    const float* beta  = (const float*)d_in[8];
    float* out = (float*)d_out;

    char* ws = (char*)d_ws;
    size_t off = 0;
    auto alloc = [&](size_t bytes) -> void* {
        void* p = ws + off;
        off += (bytes + 255) & ~(size_t)255;
        return p;
    };
    bf16_t* Xb = (bf16_t*)alloc((size_t)Mrows * Cdim * 2);
    bf16_t* Tq = (bf16_t*)alloc((size_t)Cdim * Udim * 2);
    bf16_t* Tk = (bf16_t*)alloc((size_t)Cdim * Udim * 2);
    bf16_t* Tv = (bf16_t*)alloc((size_t)Cdim * Udim * 2);
    f16_t*  Qb = (f16_t*)alloc((size_t)Mrows * Udim * 2);
    f16_t*  Kb = (f16_t*)alloc((size_t)Mrows * Udim * 2);
    f16_t*  Vtb = (f16_t*)alloc((size_t)Mrows * Udim * 2);
    bf16_t* Rb = (bf16_t*)alloc((size_t)Mrows * Udim * 2);
    float*  stats = (float*)alloc(4 * sizeof(float));

    prep<<<dim3(16, 16, 4), 256, 0, stream>>>(X, Wq, Wk, Wv, Xb, Tq, Tk, Tv, stats);
    gemm_qkv<<<dim3(8, 32, 3), 256, 0, stream>>>(Xb, Tq, Tk, Tv, bq, bk, bv, Qb, Kb, Vtb);
    attn7<<<dim3(1024), 256, 0, stream>>>(Qb, Kb, Vtb, X, Rb, stats);
    ln_norm<<<dim3(2048), 256, 0, stream>>>(Rb, gamma, beta, stats, out);
}